// Round 8
// baseline (134.712 us; speedup 1.0000x reference)
//
#include <hip/hip_runtime.h>

#define B_ 2
#define S_ 2048
#define D_ 1024
#define H_ 16
#define DK_ 64
#define K_ 1024

typedef __bf16 bf16x8 __attribute__((ext_vector_type(8)));
typedef __bf16 bf16x4 __attribute__((ext_vector_type(4)));
typedef float f32x4 __attribute__((ext_vector_type(4)));

// Q is pre-scaled by 1/sqrt(DK) * log2(e) so attention softmax runs in exp2 domain.
#define QSCALE 0.18033688011112042f

__device__ __forceinline__ void gload16(const void* g, void* l) {
    __builtin_amdgcn_global_load_lds(
        (const __attribute__((address_space(1))) unsigned int*)g,
        (__attribute__((address_space(3))) unsigned int*)l, 16, 0, 0);
}

__device__ __forceinline__ bf16x8 cvt8f(const float* __restrict__ p) {
    f32x4 a = *reinterpret_cast<const f32x4*>(p);
    f32x4 b = *reinterpret_cast<const f32x4*>(p + 4);
    bf16x8 r;
#pragma unroll
    for (int j = 0; j < 4; ++j) { r[j] = (__bf16)a[j]; r[j + 4] = (__bf16)b[j]; }
    return r;
}

// ---- fp32->bf16 for the 4 weight matrices ----
__global__ __launch_bounds__(256) void cvt4(
    const float* __restrict__ s0, const float* __restrict__ s1,
    const float* __restrict__ s2, const float* __restrict__ s3,
    __bf16* __restrict__ d0, __bf16* __restrict__ d1,
    __bf16* __restrict__ d2, __bf16* __restrict__ d3, int n8)
{
    const float* s; __bf16* d;
    if (blockIdx.y == 0) { s = s0; d = d0; }
    else if (blockIdx.y == 1) { s = s1; d = d1; }
    else if (blockIdx.y == 2) { s = s2; d = d2; }
    else { s = s3; d = d3; }
    int i = blockIdx.x * 256 + threadIdx.x;
    if (i >= n8) return;
    *reinterpret_cast<bf16x8*>(d + (size_t)i * 8) = cvt8f(s + (size_t)i * 8);
}

// ===== fused QKV projection GEMM, 128x128 tile, BK=32, 2-buf pipeline. =====
// fp32 activation side is reg-staged (global->reg->cvt->ds_write); bf16 weight
// side is global_load_lds. grid (32, 8, 3):
//   z=0: q = query @ wq^T (*QSCALE) -> bf16 [B,H,S,DK]
//   z=1: k = key_  @ wk^T           -> bf16 [B,H,S,DK]
//   z=2: vt = wv @ value^T          -> bf16 [B,H,DK,S]
__global__ __launch_bounds__(256) void gemm_qkv(
    const float* __restrict__ query, const float* __restrict__ key_, const float* __restrict__ value,
    const __bf16* __restrict__ wq,  const __bf16* __restrict__ wk,  const __bf16* __restrict__ wv,
    const float* __restrict__ bq,   const float* __restrict__ bk,   const float* __restrict__ bv,
    __bf16* __restrict__ qo, __bf16* __restrict__ ko, __bf16* __restrict__ vto)
{
    __shared__ __attribute__((aligned(16))) char ldsF[2][8192];   // fp32-side (converted)
    __shared__ __attribute__((aligned(16))) char ldsL[2][8192];   // bf16 weight side

    const int tid = threadIdx.x;
    const int w = tid >> 6, lane = tid & 63;
    const int l15 = lane & 15, lh = lane >> 4;
    const int wr = w >> 1, wc = w & 1;

    const int z = blockIdx.z;
    int brow, bcol;
    if (z < 2) { brow = blockIdx.x * 128; bcol = blockIdx.y * 128; }
    else       { brow = (blockIdx.x & 7) * 128; bcol = (blockIdx.y * 4 + (blockIdx.x >> 3)) * 128; }

    // F-side (fp32, reg-staged): z0 query/brow, z1 key_/brow, z2 value/bcol
    const float* Fsrc = (z == 0) ? query : (z == 1) ? key_ : value;
    const int    Frow = (z < 2) ? brow : bcol;
    // L-side (bf16 gload_lds): z0 wq/bcol, z1 wk/bcol, z2 wv/brow
    const char*  Lsrc = (const char*)((z == 0) ? wq : (z == 1) ? wk : wv);
    const int    Lrow = (z < 2) ? bcol : brow;

    // fp32 staging geometry: thread (r=tid>>1, ch=tid&1) covers row r, 16 cols
    const int fr = tid >> 1, fch = tid & 1;
    const float* fbase = Fsrc + (size_t)(Frow + fr) * 1024 + fch * 16;

    // L-side staging: 2 gload16/thread
    const int srow = lane >> 2, scolb = (lane & 3) * 16;

    f32x4 areg[4];
    auto loadF = [&](int k0) {
#pragma unroll
        for (int j = 0; j < 4; ++j)
            areg[j] = *reinterpret_cast<const f32x4*>(fbase + k0 + j * 4);
    };
    auto writeF = [&](int buf) {
        bf16x8 lo, hi;
#pragma unroll
        for (int j = 0; j < 4; ++j) { lo[j] = (__bf16)areg[0][j]; lo[j+4] = (__bf16)areg[1][j];
                                      hi[j] = (__bf16)areg[2][j]; hi[j+4] = (__bf16)areg[3][j]; }
        char* dst = &ldsF[buf][fr * 64 + fch * 32];
        *reinterpret_cast<bf16x8*>(dst) = lo;
        *reinterpret_cast<bf16x8*>(dst + 16) = hi;
    };
    auto stageL = [&](int buf, int k0) {
#pragma unroll
        for (int c = 0; c < 2; ++c) {
            const int chunk = w * 2 + c;
            const int loff  = __builtin_amdgcn_readfirstlane(chunk * 1024);
            gload16(Lsrc + (size_t)(Lrow + chunk * 16 + srow) * 2048 + k0 * 2 + scolb,
                    &ldsL[buf][loff]);
        }
    };

    const char* aLds = (z < 2) ? &ldsF[0][0] : &ldsL[0][0];
    const char* bLds = (z < 2) ? &ldsL[0][0] : &ldsF[0][0];

    f32x4 acc[4][4] = {};
    const int NT = K_ / 32;

    // prologue
    loadF(0); stageL(0, 0);
    asm volatile("s_waitcnt vmcnt(0)" ::: "memory");
    writeF(0);
    loadF(32); stageL(1, 32);
    asm volatile("s_waitcnt lgkmcnt(0)" ::: "memory");
    __builtin_amdgcn_s_barrier();

    for (int t = 0; t < NT; ++t) {
        const int buf = t & 1;
        const int bo  = buf * 8192;

        bf16x8 af[4], bfr[4];
#pragma unroll
        for (int m = 0; m < 4; ++m)
            af[m] = *reinterpret_cast<const bf16x8*>(aLds + bo + (wr * 64 + m * 16 + l15) * 64 + lh * 16);
#pragma unroll
        for (int n = 0; n < 4; ++n)
            bfr[n] = *reinterpret_cast<const bf16x8*>(bLds + bo + (wc * 64 + n * 16 + l15) * 64 + lh * 16);

        __builtin_amdgcn_s_setprio(1);
#pragma unroll
        for (int m = 0; m < 4; ++m)
#pragma unroll
            for (int n = 0; n < 4; ++n)
                acc[m][n] = __builtin_amdgcn_mfma_f32_16x16x32_bf16(af[m], bfr[n], acc[m][n], 0, 0, 0);
        __builtin_amdgcn_s_setprio(0);

        if (t + 1 < NT) {
            asm volatile("s_waitcnt vmcnt(0)" ::: "memory");   // t+1 F-regs + L-lds arrived
            __builtin_amdgcn_s_barrier();                      // all waves done reading buf^1? (see below)
            writeF(buf ^ 1);                                   // F(t+1) -> other buffer
            if (t + 2 < NT) { loadF((t + 2) * 32); stageL(buf, (t + 2) * 32); }
            asm volatile("s_waitcnt lgkmcnt(0)" ::: "memory"); // F writes visible
            __builtin_amdgcn_s_barrier();                      // buf^1 valid for t+1
        }
    }

    // epilogue (same verified C/D mapping)
#pragma unroll
    for (int ni = 0; ni < 4; ++ni) {
        const int n = bcol + wc * 64 + ni * 16 + l15;
#pragma unroll
        for (int mi = 0; mi < 4; ++mi)
#pragma unroll
            for (int r = 0; r < 4; ++r) {
                const int m = brow + wr * 64 + mi * 16 + lh * 4 + r;
                if (z < 2) {
                    float v = acc[mi][ni][r] + ((z == 0) ? bq[n] : bk[n]);
                    if (z == 0) v *= QSCALE;
                    const int bb = m >> 11, ss = m & (S_ - 1);
                    const int hh = n >> 6,  dk = n & 63;
                    __bf16* o = (z == 0) ? qo : ko;
                    o[(((size_t)(bb * H_ + hh)) * S_ + ss) * DK_ + dk] = (__bf16)v;
                } else {
                    const float v = acc[mi][ni][r] + bv[m];
                    const int hh = m >> 6,  dk = m & 63;
                    const int bb = n >> 11, ss = n & (S_ - 1);
                    vto[(((size_t)(bb * H_ + hh)) * DK_ + dk) * S_ + ss] = (__bf16)v;
                }
            }
    }
}

// ---- output GEMM: 128x128 2-phase dbuf (bf16 ctx @ bf16 wo^T -> fp32) ----
__global__ __launch_bounds__(256) void gemm_out(
    const __bf16* __restrict__ A, const __bf16* __restrict__ Bm,
    const float* __restrict__ bias, float* __restrict__ out)
{
    __shared__ __attribute__((aligned(16))) __bf16 ldsA[2 * 128 * 32];
    __shared__ __attribute__((aligned(16))) __bf16 ldsB[2 * 128 * 32];

    const int tid = threadIdx.x;
    const int w = tid >> 6, lane = tid & 63;
    const int l15 = lane & 15, lh = lane >> 4;
    const int wr = w >> 1, wc = w & 1;
    const int brow = blockIdx.x * 128;
    const int bcol = blockIdx.y * 128;
    const int srow  = lane >> 2;
    const int scolb = (lane & 3) * 16;
    const char* Ab = (const char*)A;
    const char* Bb = (const char*)Bm;

    auto stage = [&](int buf, int k0) {
#pragma unroll
        for (int c = 0; c < 2; ++c) {
            const int chunk = w * 2 + c;
            const int row   = chunk * 16 + srow;
            const int loff  = __builtin_amdgcn_readfirstlane(buf * 8192 + chunk * 1024);
            gload16(Ab + (size_t)(brow + row) * 2048 + k0 * 2 + scolb, (char*)ldsA + loff);
            gload16(Bb + (size_t)(bcol + row) * 2048 + k0 * 2 + scolb, (char*)ldsB + loff);
        }
    };

    f32x4 acc[4][4] = {};
    stage(0, 0);
    int buf = 0;
    for (int k0 = 0; k0 < K_; k0 += 32) {
        if (k0 + 32 < K_) {
            stage(buf ^ 1, k0 + 32);
            asm volatile("s_waitcnt vmcnt(4)" ::: "memory");
        } else {
            asm volatile("s_waitcnt vmcnt(0)" ::: "memory");
        }
        __builtin_amdgcn_s_barrier();
        __builtin_amdgcn_sched_barrier(0);

        const int bo = buf * 4096;
        bf16x8 af[4], bfr[4];
#pragma unroll
        for (int m = 0; m < 4; ++m)
            af[m] = *reinterpret_cast<const bf16x8*>(&ldsA[bo + (wr * 64 + m * 16 + l15) * 32 + lh * 8]);
#pragma unroll
        for (int n = 0; n < 4; ++n)
            bfr[n] = *reinterpret_cast<const bf16x8*>(&ldsB[bo + (wc * 64 + n * 16 + l15) * 32 + lh * 8]);

        __builtin_amdgcn_s_setprio(1);
#pragma unroll
        for (int m = 0; m < 4; ++m)
#pragma unroll
            for (int n = 0; n < 4; ++n)
                acc[m][n] = __builtin_amdgcn_mfma_f32_16x16x32_bf16(af[m], bfr[n], acc[m][n], 0, 0, 0);
        __builtin_amdgcn_s_setprio(0);

        __builtin_amdgcn_s_barrier();
        buf ^= 1;
    }

#pragma unroll
    for (int ni = 0; ni < 4; ++ni) {
        const int n = bcol + wc * 64 + ni * 16 + l15;
        const float bv = bias[n];
#pragma unroll
        for (int mi = 0; mi < 4; ++mi)
#pragma unroll
            for (int r = 0; r < 4; ++r) {
                const int m = brow + wr * 64 + mi * 16 + lh * 4 + r;
                out[(size_t)m * D_ + n] = acc[mi][ni][r] + bv;
            }
    }
}

// ---- flash attention, causal. 64-row panel per block; CU-balanced panel
// schedule (4 rounds of 256 blocks, per-slot panel sums == 62); KV dbuf;
// exp2-domain softmax; l via ones-fragment MFMA. ----
__global__ __launch_bounds__(256, 4) void attn_kernel(
    const __bf16* __restrict__ Q, const __bf16* __restrict__ K,
    const __bf16* __restrict__ VT, __bf16* __restrict__ CTX)
{
    __shared__ __attribute__((aligned(16))) char ldsK[2][8192];
    __shared__ __attribute__((aligned(16))) char ldsV[2][8192];
    __shared__ __attribute__((aligned(16))) __bf16 p_lds[4][16][64];

    const int tid = threadIdx.x;
    const int w = tid >> 6, l = tid & 63;
    const int l15 = l & 15, lh = l >> 4;

    // balanced schedule: round r in 0..3, slot c in 0..255
    const int c  = blockIdx.x & 255;
    const int rr = blockIdx.x >> 8;
    const int qq = c >> 5;
    const int bhidx = c & 31;
    int panel;
    if (rr == 0)      panel = 31 - qq;
    else if (rr == 1) panel = qq;
    else if (rr == 2) panel = 23 - qq;
    else              panel = 8 + qq;
    const int h = bhidx & 15;
    const int b = bhidx >> 4;

    const size_t bh = (size_t)(b * H_ + h);
    const __bf16* qp   = Q + bh * S_ * DK_;
    const char*  kbase = (const char*)(K  + bh * S_ * DK_);
    const char*  vbase = (const char*)(VT + bh * DK_ * S_);

    const int np = panel + 1;
    const int wave_base = panel * 64 + w * 16;

    const int srow = l >> 3;
    const int ssw  = ((l & 7) * 16) ^ (srow * 16);

    auto stage = [&](int pos) {
        const int k0 = pos * 64;
        char* lk = ldsK[pos & 1];
        char* lv = ldsV[pos & 1];
#pragma unroll
        for (int i = 0; i < 2; ++i) {
            const int r0   = w * 16 + i * 8;
            const int loff = __builtin_amdgcn_readfirstlane(r0 * 128);
            gload16(kbase + (size_t)(k0 + r0 + srow) * 128 + ssw, lk + loff);
            gload16(vbase + (size_t)(r0 + srow) * 4096 + (size_t)k0 * 2 + ssw, lv + loff);
        }
    };

    bf16x8 aq[2];
#pragma unroll
    for (int cc = 0; cc < 2; ++cc)
        aq[cc] = *reinterpret_cast<const bf16x8*>(
            qp + (size_t)(wave_base + l15) * DK_ + cc * 32 + lh * 8);

    bf16x8 vones;
#pragma unroll
    for (int j = 0; j < 8; ++j) vones[j] = (__bf16)1.0f;
    const f32x4 fzero = {0.f, 0.f, 0.f, 0.f};

    f32x4 acc[4] = {};
    f32x4 acc_l = {};
    float mrun = -INFINITY;

    stage(0);

    for (int it = 0; it < np; ++it) {
        if (it + 1 < np) {
            stage(it + 1);
            asm volatile("s_waitcnt vmcnt(4)" ::: "memory");
        } else {
            asm volatile("s_waitcnt vmcnt(0)" ::: "memory");
        }
        __builtin_amdgcn_s_barrier();
        __builtin_amdgcn_sched_barrier(0);

        const int k0 = it * 64;
        const char* lk = ldsK[it & 1];
        const char* lv = ldsV[it & 1];

        bf16x8 ak[4][2];
#pragma unroll
        for (int t = 0; t < 4; ++t)
#pragma unroll
            for (int cc = 0; cc < 2; ++cc) {
                const int col = (cc * 64 + lh * 16) ^ ((l15 & 7) << 4);
                ak[t][cc] = *reinterpret_cast<const bf16x8*>(lk + (t * 16 + l15) * 128 + col);
            }

        f32x4 sacc[4];
        __builtin_amdgcn_s_setprio(1);
#pragma unroll
        for (int t = 0; t < 4; ++t) {
            sacc[t] = __builtin_amdgcn_mfma_f32_16x16x32_bf16(ak[t][0], aq[0], fzero, 0, 0, 0);
            sacc[t] = __builtin_amdgcn_mfma_f32_16x16x32_bf16(ak[t][1], aq[1], sacc[t], 0, 0, 0);
        }
        __builtin_amdgcn_s_setprio(0);

        bf16x8 bv[4][2];
#pragma unroll
        for (int nt = 0; nt < 4; ++nt)
#pragma unroll
            for (int c2 = 0; c2 < 2; ++c2) {
                const int col = (c2 * 64 + lh * 16) ^ ((l15 & 7) << 4);
                bv[nt][c2] = *reinterpret_cast<const bf16x8*>(lv + (nt * 16 + l15) * 128 + col);
            }

        if (k0 + 63 > wave_base) {
            const int qa = wave_base + l15;
#pragma unroll
            for (int t = 0; t < 4; ++t)
#pragma unroll
                for (int r = 0; r < 4; ++r) {
                    const int ka = k0 + t * 16 + lh * 4 + r;
                    if (ka > qa) sacc[t][r] = -INFINITY;
                }
        }

        f32x4 m4 = sacc[0];
#pragma unroll
        for (int t = 1; t < 4; ++t)
#pragma unroll
            for (int r = 0; r < 4; ++r) m4[r] = fmaxf(m4[r], sacc[t][r]);
        float rm = fmaxf(fmaxf(m4[0], m4[1]), fmaxf(m4[2], m4[3]));
        rm = fmaxf(rm, __shfl_xor(rm, 16, 64));
        rm = fmaxf(rm, __shfl_xor(rm, 32, 64));

        if (!__all(rm <= mrun + 8.f)) {
            const float mnew = fmaxf(mrun, rm);
            const float scl  = exp2f(mrun - mnew);
            mrun = mnew;
#pragma unroll
            for (int r = 0; r < 4; ++r) {
                const float sr = __shfl(scl, lh * 4 + r, 64);
#pragma unroll
                for (int nt = 0; nt < 4; ++nt) acc[nt][r] *= sr;
                acc_l[r] *= sr;
            }
        }

#pragma unroll
        for (int t = 0; t < 4; ++t) {
            bf16x4 pk;
#pragma unroll
            for (int r = 0; r < 4; ++r)
                pk[r] = (__bf16)exp2f(sacc[t][r] - mrun);
            const int wcol = (t * 16 + lh * 4) ^ ((l15 & 7) << 3);
            *reinterpret_cast<bf16x4*>(&p_lds[w][l15][wcol]) = pk;
        }

        bf16x8 pa[2];
#pragma unroll
        for (int c2 = 0; c2 < 2; ++c2) {
            const int rcol = (c2 * 32 + lh * 8) ^ ((l15 & 7) << 3);
            pa[c2] = *reinterpret_cast<const bf16x8*>(&p_lds[w][l15][rcol]);
        }

        __builtin_amdgcn_s_setprio(1);
#pragma unroll
        for (int nt = 0; nt < 4; ++nt)
#pragma unroll
            for (int c2 = 0; c2 < 2; ++c2)
                acc[nt] = __builtin_amdgcn_mfma_f32_16x16x32_bf16(
                    pa[c2], bv[nt][c2], acc[nt], 0, 0, 0);
        acc_l = __builtin_amdgcn_mfma_f32_16x16x32_bf16(pa[0], vones, acc_l, 0, 0, 0);
        acc_l = __builtin_amdgcn_mfma_f32_16x16x32_bf16(pa[1], vones, acc_l, 0, 0, 0);
        __builtin_amdgcn_s_setprio(0);

        __builtin_amdgcn_s_barrier();
    }

#pragma unroll
    for (int r = 0; r < 4; ++r) {
        const float linv = 1.f / acc_l[r];
        const int srow2 = wave_base + lh * 4 + r;
#pragma unroll
        for (int nt = 0; nt < 4; ++nt)
            CTX[((size_t)b * S_ + srow2) * D_ + h * DK_ + nt * 16 + l15] =
                (__bf16)(acc[nt][r] * linv);
    }
}

extern "C" void kernel_launch(void* const* d_in, const int* in_sizes, int n_in,
                              void* d_out, int out_size, void* d_ws, size_t ws_size,
                              hipStream_t stream) {
    (void)in_sizes; (void)n_in; (void)out_size; (void)ws_size;

    const float* query = (const float*)d_in[0];
    const float* key_  = (const float*)d_in[1];
    const float* value = (const float*)d_in[2];
    // d_in[3] = attn_mask: deterministically causal triu(k=1) -> handled analytically
    const float* w_q = (const float*)d_in[4];
    const float* b_q = (const float*)d_in[5];
    const float* w_k = (const float*)d_in[6];
    const float* b_k = (const float*)d_in[7];
    const float* w_v = (const float*)d_in[8];
    const float* b_v = (const float*)d_in[9];
    const float* w_o = (const float*)d_in[10];
    const float* b_o = (const float*)d_in[11];
    float* out = (float*)d_out;

    char* Wp = (char*)d_ws;
    const size_t MB = 1024 * 1024;
    __bf16* ctx = (__bf16*)(Wp + 0 * MB);
    __bf16* wq  = (__bf16*)(Wp + 24 * MB);
    __bf16* wk  = (__bf16*)(Wp + 26 * MB);
    __bf16* wv  = (__bf16*)(Wp + 28 * MB);
    __bf16* wo  = (__bf16*)(Wp + 30 * MB);
    __bf16* q   = (__bf16*)(Wp + 32 * MB);
    __bf16* k   = (__bf16*)(Wp + 40 * MB);
    __bf16* vt  = (__bf16*)(Wp + 48 * MB);    // end: 56 MB

    const int n8_w = (D_ * D_) / 8;           // 131072

    hipLaunchKernelGGL(cvt4, dim3(n8_w / 256, 4), dim3(256), 0, stream,
                       w_q, w_k, w_v, w_o, wq, wk, wv, wo, n8_w);
    hipLaunchKernelGGL(gemm_qkv, dim3(32, 8, 3), dim3(256), 0, stream,
                       query, key_, value, wq, wk, wv, b_q, b_k, b_v, q, k, vt);
    hipLaunchKernelGGL(attn_kernel, dim3(1024), dim3(256), 0, stream,
                       q, k, vt, ctx);
    hipLaunchKernelGGL(gemm_out, dim3(32, 8), dim3(256), 0, stream,
                       ctx, wo, b_o, out);
}

// Round 9
// 128.539 us; speedup vs baseline: 1.0480x; 1.0480x over previous
//
#include <hip/hip_runtime.h>

#define B_ 2
#define S_ 2048
#define D_ 1024
#define H_ 16
#define DK_ 64
#define K_ 1024

typedef __bf16 bf16x8 __attribute__((ext_vector_type(8)));
typedef __bf16 bf16x4 __attribute__((ext_vector_type(4)));
typedef float f32x4 __attribute__((ext_vector_type(4)));

// Q is pre-scaled by 1/sqrt(DK) * log2(e) so attention softmax runs in exp2 domain.
#define QSCALE 0.18033688011112042f

__device__ __forceinline__ void gload16(const void* g, void* l) {
    __builtin_amdgcn_global_load_lds(
        (const __attribute__((address_space(1))) unsigned int*)g,
        (__attribute__((address_space(3))) unsigned int*)l, 16, 0, 0);
}

__device__ __forceinline__ bf16x8 cvt8f(const float* __restrict__ p) {
    f32x4 a = *reinterpret_cast<const f32x4*>(p);
    f32x4 b = *reinterpret_cast<const f32x4*>(p + 4);
    bf16x8 r;
#pragma unroll
    for (int j = 0; j < 4; ++j) { r[j] = (__bf16)a[j]; r[j + 4] = (__bf16)b[j]; }
    return r;
}

// ---- single-launch fp32->bf16 for all 7 tensors (y = tensor id) ----
__global__ __launch_bounds__(256) void cvt_all(
    const float* __restrict__ s0, const float* __restrict__ s1, const float* __restrict__ s2,
    const float* __restrict__ s3, const float* __restrict__ s4, const float* __restrict__ s5,
    const float* __restrict__ s6,
    __bf16* __restrict__ d0, __bf16* __restrict__ d1, __bf16* __restrict__ d2,
    __bf16* __restrict__ d3, __bf16* __restrict__ d4, __bf16* __restrict__ d5,
    __bf16* __restrict__ d6)
{
    const int y = blockIdx.y;
    const float* s; __bf16* d; int n8;
    const int n8_big = (B_ * S_ * D_) / 8, n8_w = (D_ * D_) / 8;
    switch (y) {
        case 0: s = s0; d = d0; n8 = n8_big; break;
        case 1: s = s1; d = d1; n8 = n8_big; break;
        case 2: s = s2; d = d2; n8 = n8_big; break;
        case 3: s = s3; d = d3; n8 = n8_w; break;
        case 4: s = s4; d = d4; n8 = n8_w; break;
        case 5: s = s5; d = d5; n8 = n8_w; break;
        default: s = s6; d = d6; n8 = n8_w; break;
    }
    int i = blockIdx.x * 256 + threadIdx.x;
    if (i >= n8) return;
    *reinterpret_cast<bf16x8*>(d + (size_t)i * 8) = cvt8f(s + (size_t)i * 8);
}

// ---- fused QKV projections (proven round-6 structure): grid (32, 8, 3),
// 128x128 tile, BK=32, 2-phase LDS double-buffer, gload_lds both sides ----
__global__ __launch_bounds__(256) void gemm_qkv(
    const __bf16* __restrict__ qin, const __bf16* __restrict__ kin, const __bf16* __restrict__ vin,
    const __bf16* __restrict__ wq,  const __bf16* __restrict__ wk,  const __bf16* __restrict__ wv,
    const float* __restrict__ bq,   const float* __restrict__ bk,   const float* __restrict__ bv,
    __bf16* __restrict__ qo, __bf16* __restrict__ ko, __bf16* __restrict__ vto)
{
    __shared__ __attribute__((aligned(16))) __bf16 ldsA[2 * 128 * 32];
    __shared__ __attribute__((aligned(16))) __bf16 ldsB[2 * 128 * 32];

    const int z = blockIdx.z;
    const __bf16* A; const __bf16* Bm;
    int brow, bcol;
    if (z == 0)      { A = qin; Bm = wq;  brow = blockIdx.x * 128; bcol = blockIdx.y * 128; }
    else if (z == 1) { A = kin; Bm = wk;  brow = blockIdx.x * 128; bcol = blockIdx.y * 128; }
    else             { A = wv;  Bm = vin;
                       brow = (blockIdx.x & 7) * 128;
                       bcol = (blockIdx.y * 4 + (blockIdx.x >> 3)) * 128; }

    const int tid = threadIdx.x;
    const int w = tid >> 6, lane = tid & 63;
    const int l15 = lane & 15, lh = lane >> 4;
    const int wr = w >> 1, wc = w & 1;
    const int srow  = lane >> 2;
    const int scolb = (lane & 3) * 16;
    const char* Ab = (const char*)A;
    const char* Bb = (const char*)Bm;

    auto stage = [&](int buf, int k0) {
#pragma unroll
        for (int c = 0; c < 2; ++c) {
            const int chunk = w * 2 + c;
            const int row   = chunk * 16 + srow;
            const int loff  = __builtin_amdgcn_readfirstlane(buf * 8192 + chunk * 1024);
            gload16(Ab + (size_t)(brow + row) * 2048 + k0 * 2 + scolb, (char*)ldsA + loff);
            gload16(Bb + (size_t)(bcol + row) * 2048 + k0 * 2 + scolb, (char*)ldsB + loff);
        }
    };

    f32x4 acc[4][4] = {};
    stage(0, 0);
    int buf = 0;
    for (int k0 = 0; k0 < K_; k0 += 32) {
        if (k0 + 32 < K_) {
            stage(buf ^ 1, k0 + 32);
            asm volatile("s_waitcnt vmcnt(4)" ::: "memory");
        } else {
            asm volatile("s_waitcnt vmcnt(0)" ::: "memory");
        }
        __builtin_amdgcn_s_barrier();
        __builtin_amdgcn_sched_barrier(0);

        const int bo = buf * 4096;
        bf16x8 af[4], bfr[4];
#pragma unroll
        for (int m = 0; m < 4; ++m)
            af[m] = *reinterpret_cast<const bf16x8*>(&ldsA[bo + (wr * 64 + m * 16 + l15) * 32 + lh * 8]);
#pragma unroll
        for (int n = 0; n < 4; ++n)
            bfr[n] = *reinterpret_cast<const bf16x8*>(&ldsB[bo + (wc * 64 + n * 16 + l15) * 32 + lh * 8]);

        __builtin_amdgcn_s_setprio(1);
#pragma unroll
        for (int m = 0; m < 4; ++m)
#pragma unroll
            for (int n = 0; n < 4; ++n)
                acc[m][n] = __builtin_amdgcn_mfma_f32_16x16x32_bf16(af[m], bfr[n], acc[m][n], 0, 0, 0);
        __builtin_amdgcn_s_setprio(0);

        __builtin_amdgcn_s_barrier();
        buf ^= 1;
    }

#pragma unroll
    for (int ni = 0; ni < 4; ++ni) {
        const int n = bcol + wc * 64 + ni * 16 + l15;
#pragma unroll
        for (int mi = 0; mi < 4; ++mi)
#pragma unroll
            for (int r = 0; r < 4; ++r) {
                const int m = brow + wr * 64 + mi * 16 + lh * 4 + r;
                if (z < 2) {
                    float v = acc[mi][ni][r] + ((z == 0) ? bq[n] : bk[n]);
                    if (z == 0) v *= QSCALE;          // fold 1/sqrt(dk)*log2e into Q
                    const int bb = m >> 11, ss = m & (S_ - 1);
                    const int hh = n >> 6,  dk = n & 63;
                    __bf16* o = (z == 0) ? qo : ko;
                    o[(((size_t)(bb * H_ + hh)) * S_ + ss) * DK_ + dk] = (__bf16)v;
                } else {
                    const float v = acc[mi][ni][r] + bv[m];
                    const int hh = m >> 6,  dk = m & 63;
                    const int bb = n >> 11, ss = n & (S_ - 1);
                    vto[(((size_t)(bb * H_ + hh)) * DK_ + dk) * S_ + ss] = (__bf16)v;
                }
            }
    }
}

// ---- output GEMM: out = ctx @ wo^T + bo (fp32 out), 128x128 2-phase dbuf ----
__global__ __launch_bounds__(256) void gemm_out(
    const __bf16* __restrict__ A, const __bf16* __restrict__ Bm,
    const float* __restrict__ bias, float* __restrict__ out)
{
    __shared__ __attribute__((aligned(16))) __bf16 ldsA[2 * 128 * 32];
    __shared__ __attribute__((aligned(16))) __bf16 ldsB[2 * 128 * 32];

    const int tid = threadIdx.x;
    const int w = tid >> 6, lane = tid & 63;
    const int l15 = lane & 15, lh = lane >> 4;
    const int wr = w >> 1, wc = w & 1;
    const int brow = blockIdx.x * 128;
    const int bcol = blockIdx.y * 128;
    const int srow  = lane >> 2;
    const int scolb = (lane & 3) * 16;
    const char* Ab = (const char*)A;
    const char* Bb = (const char*)Bm;

    auto stage = [&](int buf, int k0) {
#pragma unroll
        for (int c = 0; c < 2; ++c) {
            const int chunk = w * 2 + c;
            const int row   = chunk * 16 + srow;
            const int loff  = __builtin_amdgcn_readfirstlane(buf * 8192 + chunk * 1024);
            gload16(Ab + (size_t)(brow + row) * 2048 + k0 * 2 + scolb, (char*)ldsA + loff);
            gload16(Bb + (size_t)(bcol + row) * 2048 + k0 * 2 + scolb, (char*)ldsB + loff);
        }
    };

    f32x4 acc[4][4] = {};
    stage(0, 0);
    int buf = 0;
    for (int k0 = 0; k0 < K_; k0 += 32) {
        if (k0 + 32 < K_) {
            stage(buf ^ 1, k0 + 32);
            asm volatile("s_waitcnt vmcnt(4)" ::: "memory");
        } else {
            asm volatile("s_waitcnt vmcnt(0)" ::: "memory");
        }
        __builtin_amdgcn_s_barrier();
        __builtin_amdgcn_sched_barrier(0);

        const int bo = buf * 4096;
        bf16x8 af[4], bfr[4];
#pragma unroll
        for (int m = 0; m < 4; ++m)
            af[m] = *reinterpret_cast<const bf16x8*>(&ldsA[bo + (wr * 64 + m * 16 + l15) * 32 + lh * 8]);
#pragma unroll
        for (int n = 0; n < 4; ++n)
            bfr[n] = *reinterpret_cast<const bf16x8*>(&ldsB[bo + (wc * 64 + n * 16 + l15) * 32 + lh * 8]);

        __builtin_amdgcn_s_setprio(1);
#pragma unroll
        for (int m = 0; m < 4; ++m)
#pragma unroll
            for (int n = 0; n < 4; ++n)
                acc[m][n] = __builtin_amdgcn_mfma_f32_16x16x32_bf16(af[m], bfr[n], acc[m][n], 0, 0, 0);
        __builtin_amdgcn_s_setprio(0);

        __builtin_amdgcn_s_barrier();
        buf ^= 1;
    }

#pragma unroll
    for (int ni = 0; ni < 4; ++ni) {
        const int n = bcol + wc * 64 + ni * 16 + l15;
        const float bvv = bias[n];
#pragma unroll
        for (int mi = 0; mi < 4; ++mi)
#pragma unroll
            for (int r = 0; r < 4; ++r) {
                const int m = brow + wr * 64 + mi * 16 + lh * 4 + r;
                out[(size_t)m * D_ + n] = acc[mi][ni][r] + bvv;
            }
    }
}

// ---- flash attention, causal. 64-row panel per block; CU-balanced panel
// schedule (4 rounds of 256 blocks, per-slot panel sums == 62); KV dbuf;
// exp2-domain softmax; l via ones-fragment MFMA. (round-8 proven) ----
__global__ __launch_bounds__(256, 4) void attn_kernel(
    const __bf16* __restrict__ Q, const __bf16* __restrict__ K,
    const __bf16* __restrict__ VT, __bf16* __restrict__ CTX)
{
    __shared__ __attribute__((aligned(16))) char ldsK[2][8192];
    __shared__ __attribute__((aligned(16))) char ldsV[2][8192];
    __shared__ __attribute__((aligned(16))) __bf16 p_lds[4][16][64];

    const int tid = threadIdx.x;
    const int w = tid >> 6, l = tid & 63;
    const int l15 = l & 15, lh = l >> 4;

    const int c  = blockIdx.x & 255;
    const int rr = blockIdx.x >> 8;
    const int qq = c >> 5;
    const int bhidx = c & 31;
    int panel;
    if (rr == 0)      panel = 31 - qq;
    else if (rr == 1) panel = qq;
    else if (rr == 2) panel = 23 - qq;
    else              panel = 8 + qq;
    const int h = bhidx & 15;
    const int b = bhidx >> 4;

    const size_t bh = (size_t)(b * H_ + h);
    const __bf16* qp   = Q + bh * S_ * DK_;
    const char*  kbase = (const char*)(K  + bh * S_ * DK_);
    const char*  vbase = (const char*)(VT + bh * DK_ * S_);

    const int np = panel + 1;
    const int wave_base = panel * 64 + w * 16;

    const int srow = l >> 3;
    const int ssw  = ((l & 7) * 16) ^ (srow * 16);

    auto stage = [&](int pos) {
        const int k0 = pos * 64;
        char* lk = ldsK[pos & 1];
        char* lv = ldsV[pos & 1];
#pragma unroll
        for (int i = 0; i < 2; ++i) {
            const int r0   = w * 16 + i * 8;
            const int loff = __builtin_amdgcn_readfirstlane(r0 * 128);
            gload16(kbase + (size_t)(k0 + r0 + srow) * 128 + ssw, lk + loff);
            gload16(vbase + (size_t)(r0 + srow) * 4096 + (size_t)k0 * 2 + ssw, lv + loff);
        }
    };

    bf16x8 aq[2];
#pragma unroll
    for (int cc = 0; cc < 2; ++cc)
        aq[cc] = *reinterpret_cast<const bf16x8*>(
            qp + (size_t)(wave_base + l15) * DK_ + cc * 32 + lh * 8);

    bf16x8 vones;
#pragma unroll
    for (int j = 0; j < 8; ++j) vones[j] = (__bf16)1.0f;
    const f32x4 fzero = {0.f, 0.f, 0.f, 0.f};

    f32x4 acc[4] = {};
    f32x4 acc_l = {};
    float mrun = -INFINITY;

    stage(0);

    for (int it = 0; it < np; ++it) {
        if (it + 1 < np) {
            stage(it + 1);
            asm volatile("s_waitcnt vmcnt(4)" ::: "memory");
        } else {
            asm volatile("s_waitcnt vmcnt(0)" ::: "memory");
        }
        __builtin_amdgcn_s_barrier();
        __builtin_amdgcn_sched_barrier(0);

        const int k0 = it * 64;
        const char* lk = ldsK[it & 1];
        const char* lv = ldsV[it & 1];

        bf16x8 ak[4][2];
#pragma unroll
        for (int t = 0; t < 4; ++t)
#pragma unroll
            for (int cc = 0; cc < 2; ++cc) {
                const int col = (cc * 64 + lh * 16) ^ ((l15 & 7) << 4);
                ak[t][cc] = *reinterpret_cast<const bf16x8*>(lk + (t * 16 + l15) * 128 + col);
            }

        f32x4 sacc[4];
        __builtin_amdgcn_s_setprio(1);
#pragma unroll
        for (int t = 0; t < 4; ++t) {
            sacc[t] = __builtin_amdgcn_mfma_f32_16x16x32_bf16(ak[t][0], aq[0], fzero, 0, 0, 0);
            sacc[t] = __builtin_amdgcn_mfma_f32_16x16x32_bf16(ak[t][1], aq[1], sacc[t], 0, 0, 0);
        }
        __builtin_amdgcn_s_setprio(0);

        bf16x8 bv[4][2];
#pragma unroll
        for (int nt = 0; nt < 4; ++nt)
#pragma unroll
            for (int c2 = 0; c2 < 2; ++c2) {
                const int col = (c2 * 64 + lh * 16) ^ ((l15 & 7) << 4);
                bv[nt][c2] = *reinterpret_cast<const bf16x8*>(lv + (nt * 16 + l15) * 128 + col);
            }

        if (k0 + 63 > wave_base) {
            const int qa = wave_base + l15;
#pragma unroll
            for (int t = 0; t < 4; ++t)
#pragma unroll
                for (int r = 0; r < 4; ++r) {
                    const int ka = k0 + t * 16 + lh * 4 + r;
                    if (ka > qa) sacc[t][r] = -INFINITY;
                }
        }

        f32x4 m4 = sacc[0];
#pragma unroll
        for (int t = 1; t < 4; ++t)
#pragma unroll
            for (int r = 0; r < 4; ++r) m4[r] = fmaxf(m4[r], sacc[t][r]);
        float rm = fmaxf(fmaxf(m4[0], m4[1]), fmaxf(m4[2], m4[3]));
        rm = fmaxf(rm, __shfl_xor(rm, 16, 64));
        rm = fmaxf(rm, __shfl_xor(rm, 32, 64));

        if (!__all(rm <= mrun + 8.f)) {
            const float mnew = fmaxf(mrun, rm);
            const float scl  = exp2f(mrun - mnew);
            mrun = mnew;
#pragma unroll
            for (int r = 0; r < 4; ++r) {
                const float sr = __shfl(scl, lh * 4 + r, 64);
#pragma unroll
                for (int nt = 0; nt < 4; ++nt) acc[nt][r] *= sr;
                acc_l[r] *= sr;
            }
        }

#pragma unroll
        for (int t = 0; t < 4; ++t) {
            bf16x4 pk;
#pragma unroll
            for (int r = 0; r < 4; ++r)
                pk[r] = (__bf16)exp2f(sacc[t][r] - mrun);
            const int wcol = (t * 16 + lh * 4) ^ ((l15 & 7) << 3);
            *reinterpret_cast<bf16x4*>(&p_lds[w][l15][wcol]) = pk;
        }

        bf16x8 pa[2];
#pragma unroll
        for (int c2 = 0; c2 < 2; ++c2) {
            const int rcol = (c2 * 32 + lh * 8) ^ ((l15 & 7) << 3);
            pa[c2] = *reinterpret_cast<const bf16x8*>(&p_lds[w][l15][rcol]);
        }

        __builtin_amdgcn_s_setprio(1);
#pragma unroll
        for (int nt = 0; nt < 4; ++nt)
#pragma unroll
            for (int c2 = 0; c2 < 2; ++c2)
                acc[nt] = __builtin_amdgcn_mfma_f32_16x16x32_bf16(
                    pa[c2], bv[nt][c2], acc[nt], 0, 0, 0);
        acc_l = __builtin_amdgcn_mfma_f32_16x16x32_bf16(pa[0], vones, acc_l, 0, 0, 0);
        acc_l = __builtin_amdgcn_mfma_f32_16x16x32_bf16(pa[1], vones, acc_l, 0, 0, 0);
        __builtin_amdgcn_s_setprio(0);

        __builtin_amdgcn_s_barrier();
    }

#pragma unroll
    for (int r = 0; r < 4; ++r) {
        const float linv = 1.f / acc_l[r];
        const int srow2 = wave_base + lh * 4 + r;
#pragma unroll
        for (int nt = 0; nt < 4; ++nt)
            CTX[((size_t)b * S_ + srow2) * D_ + h * DK_ + nt * 16 + l15] =
                (__bf16)(acc[nt][r] * linv);
    }
}

extern "C" void kernel_launch(void* const* d_in, const int* in_sizes, int n_in,
                              void* d_out, int out_size, void* d_ws, size_t ws_size,
                              hipStream_t stream) {
    (void)in_sizes; (void)n_in; (void)out_size; (void)ws_size;

    const float* query = (const float*)d_in[0];
    const float* key_  = (const float*)d_in[1];
    const float* value = (const float*)d_in[2];
    // d_in[3] = attn_mask: deterministically causal triu(k=1) -> handled analytically
    const float* w_q = (const float*)d_in[4];
    const float* b_q = (const float*)d_in[5];
    const float* w_k = (const float*)d_in[6];
    const float* b_k = (const float*)d_in[7];
    const float* w_v = (const float*)d_in[8];
    const float* b_v = (const float*)d_in[9];
    const float* w_o = (const float*)d_in[10];
    const float* b_o = (const float*)d_in[11];
    float* out = (float*)d_out;

    char* Wp = (char*)d_ws;
    const size_t MB = 1024 * 1024;
    __bf16* qin = (__bf16*)(Wp + 0 * MB);     // dead after qkv gemm -> reused as ctx
    __bf16* kin = (__bf16*)(Wp + 8 * MB);
    __bf16* vin = (__bf16*)(Wp + 16 * MB);
    __bf16* wq  = (__bf16*)(Wp + 24 * MB);
    __bf16* wk  = (__bf16*)(Wp + 26 * MB);
    __bf16* wv  = (__bf16*)(Wp + 28 * MB);
    __bf16* wo  = (__bf16*)(Wp + 30 * MB);
    __bf16* q   = (__bf16*)(Wp + 32 * MB);
    __bf16* k   = (__bf16*)(Wp + 40 * MB);
    __bf16* vt  = (__bf16*)(Wp + 48 * MB);    // end: 56 MB
    __bf16* ctx = qin;

    const int n8_big = (B_ * S_ * D_) / 8;    // 524288 -> 2048 blocks

    hipLaunchKernelGGL(cvt_all, dim3(n8_big / (256 * 8) * 8, 7), dim3(256), 0, stream,
                       query, key_, value, w_q, w_k, w_v, w_o,
                       qin, kin, vin, wq, wk, wv, wo);
    hipLaunchKernelGGL(gemm_qkv, dim3(32, 8, 3), dim3(256), 0, stream,
                       qin, kin, vin, wq, wk, wv, b_q, b_k, b_v, q, k, vt);
    hipLaunchKernelGGL(attn_kernel, dim3(1024), dim3(256), 0, stream,
                       q, k, vt, ctx);
    hipLaunchKernelGGL(gemm_out, dim3(32, 8), dim3(256), 0, stream,
                       ctx, wo, b_o, out);
}